// Round 2
// baseline (902.042 us; speedup 1.0000x reference)
//
#include <hip/hip_runtime.h>
#include <hip/hip_bf16.h>
#include <stdint.h>

#define B_ 32
#define N_ 2048
#define D_ 1024
#define H_ 16

#define NT 8           // 8 x 16-row tiles per block (128 rows/block, grid 512)
#define RPB 1032       // bf16 row stride in LDS (shorts): 2064 B, 16B-pad rotation

typedef __attribute__((ext_vector_type(8))) short short8;
typedef __attribute__((ext_vector_type(4))) float f32x4;

__device__ __forceinline__ unsigned short f2bf(float x) {
    unsigned u = __float_as_uint(x);
    u += 0x7FFFu + ((u >> 16) & 1u);   // RNE
    return (unsigned short)(u >> 16);
}
__device__ __forceinline__ float bflo(unsigned u) { return __uint_as_float(u << 16); }

// pack 8 f32 -> short8 bf16 (RNE packed cvt)
__device__ __forceinline__ short8 cvt8(float4 a, float4 b) {
    union { __hip_bfloat162 h[4]; short8 s; } u;
    u.h[0] = __float22bfloat162_rn(make_float2(a.x, a.y));
    u.h[1] = __float22bfloat162_rn(make_float2(a.z, a.w));
    u.h[2] = __float22bfloat162_rn(make_float2(b.x, b.y));
    u.h[3] = __float22bfloat162_rn(make_float2(b.z, b.w));
    return u.s;
}

// ---------------------------------------------------------------------------
// prep_k (fused): blocks 0..63 (h=bx>>2, dg=bx&3):
//   phase 1: q_h[j] = query . w_q[64h+j,:] + b_q[64h+j]      (j in [0,64))
//   phase 2: R[h][d] = 0.125 * sum_j q_h[j] w_k[64h+j][d], d in [256dg,+256),
//            packed directly as bf16 MFMA A-fragments.
// blocks 64..95: any_ws[b] = OR over mask row (b = bx-64).
// ---------------------------------------------------------------------------
__global__ __launch_bounds__(256) void prep_k(const float* __restrict__ query,
        const float* __restrict__ w_q, const float* __restrict__ b_q,
        const float* __restrict__ w_k, const int* __restrict__ mask,
        unsigned short* __restrict__ rAf, int* __restrict__ any_ws) {
    __shared__ __align__(16) float qv[1024];
    __shared__ float qp[64][5];
    __shared__ float qh[64];
    __shared__ int wf[4];
    int bx = blockIdx.x, t = threadIdx.x;
    if (bx < 64) {
        int h = bx >> 2, dg = bx & 3;
        *(float4*)&qv[4 * t] = *(const float4*)&query[4 * t];
        __syncthreads();
        // ---- phase 1: q row (64 outputs, 4 threads per output) ----
        {
            int j = t >> 2, sub = t & 3;
            const float4* wq4 = (const float4*)(w_q + (size_t)(h * 64 + j) * 1024);
            const float4* qv4 = (const float4*)qv;
            float a = 0.f;
            #pragma unroll 8
            for (int kk = 0; kk < 64; kk++) {
                float4 wv = wq4[sub * 64 + kk];
                float4 vv = qv4[sub * 64 + kk];
                a += wv.x * vv.x + wv.y * vv.y + wv.z * vv.z + wv.w * vv.w;
            }
            qp[j][sub] = a;
        }
        __syncthreads();
        if (t < 64)
            qh[t] = qp[t][0] + qp[t][1] + qp[t][2] + qp[t][3] + b_q[h * 64 + t];
        __syncthreads();
        // ---- phase 2: R slice, pack A-fragment ----
        int d = dg * 256 + t;
        float acc = 0.f;
        #pragma unroll 8
        for (int j = 0; j < 64; j++)
            acc += qh[j] * w_k[(size_t)(h * 64 + j) * 1024 + d];
        acc *= 0.125f;                       // 1/sqrt(64) folded into R
        int i = d >> 5, fq = (d >> 3) & 3, jj = d & 7;
        int lane = (fq << 4) | h;            // A[m=lane&15][k=(lane>>4)*8+j]
        rAf[(size_t)(i * 64 + lane) * 8 + jj] = f2bf(acc);
    } else {
        int b = bx - 64;
        int v = 0;
        for (int k = 0; k < 8; k++) v |= mask[b * N_ + k * 256 + t];
        unsigned long long bal = __ballot(v != 0);
        int w = t >> 6;
        if ((t & 63) == 0) wf[w] = (bal != 0ull) ? 1 : 0;
        __syncthreads();
        if (t == 0) any_ws[b] = wf[0] | wf[1] | wf[2] | wf[3];
    }
}

// ---------------------------------------------------------------------------
// main_k v2: grid 512 (b=bx>>4, chunk c=bx&15 -> 128 rows, 8 x 16-row tiles).
// z tile in LDS as bf16 (reg-staged, double-buffered): LDS 71.7 KB -> 2
// blocks/CU (occupancy 2 waves/SIMD vs 1 before). Score phase reads MFMA
// B-frags DIRECTLY via ds_read_b128 (no per-wave cvt8 repack). Staging is
// global->reg->cvt->ds_write, split into 3 batches (4/4/8 rows) issued early
// and written after compute phases (T14) to hide HBM latency under compute.
// Mask row preloaded into LDS (kills per-tile global-latency stalls).
// ctx accumulates from bf16 z (adds ~5e-5 abs error; verified safe margin).
// ---------------------------------------------------------------------------
__global__ __launch_bounds__(256, 2) void main_k(const float* __restrict__ z,
        const int* __restrict__ mask, const int* __restrict__ any_ws,
        const unsigned short* __restrict__ rAf,
        unsigned short* __restrict__ part, float* __restrict__ l_part) {
    __shared__ __align__(16) unsigned short ztb[2][16 * RPB];  // 66,048 B
    __shared__ __align__(16) float Ew[4][16][20];              // 5,120 B (pad 20)
    __shared__ int mlds[128];                                  // 512 B
    int bx = blockIdx.x, t = threadIdx.x;
    int b = bx >> 4, c = bx & 15;
    int n0 = c * 128;
    int w = t >> 6, l = t & 63;
    int frow = l & 15, fquad = l >> 4;
    int anyb = any_ws[b];

    // preload all 32 A-fragments (128 VGPRs)
    short8 rA[32];
    {
        const short8* rA8 = (const short8*)rAf;
        #pragma unroll
        for (int i = 0; i < 32; i++) rA[i] = rA8[i * 64 + l];
    }
    const float* zb = z + (size_t)b * N_ * D_ + (size_t)n0 * D_;

    if (t < 128) mlds[t] = mask[b * N_ + n0 + t];

    float4 ctx[16];
    #pragma unroll
    for (int h = 0; h < 16; h++) ctx[h] = make_float4(0.f, 0.f, 0.f, 0.f);
    float l4[4] = {0.f, 0.f, 0.f, 0.f};

    // --- reg-staging: 4-row batch = wave w stages row rb+w; lane covers
    // 16B-chunks l and l+64 of the row (writes: full-wave contiguous 1KB) ---
    float4 ga[4], gb[4], gc[8];
    #define ISSUE4(g, tile, rb)                                                   \
        {                                                                         \
            const float4* src = (const float4*)(zb + (size_t)(tile) * 16 * D_ +   \
                                                (size_t)((rb) + w) * D_);         \
            g[0] = src[2 * l];       g[1] = src[2 * l + 1];                       \
            g[2] = src[2 * (l + 64)]; g[3] = src[2 * (l + 64) + 1];               \
        }
    #define WRITE4(g, pp, rb)                                                     \
        {                                                                         \
            unsigned short* dst = &ztb[(pp)][((rb) + w) * RPB];                   \
            *(short8*)(dst + l * 8) = cvt8(g[0], g[1]);                           \
            *(short8*)(dst + (l + 64) * 8) = cvt8(g[2], g[3]);                    \
        }
    #define ISSUE8(g, tile)                                                       \
        {                                                                         \
            const float4* s0 = (const float4*)(zb + (size_t)(tile) * 16 * D_ +    \
                                               (size_t)(8 + 2 * w) * D_);         \
            const float4* s1 = (const float4*)(zb + (size_t)(tile) * 16 * D_ +    \
                                               (size_t)(9 + 2 * w) * D_);         \
            g[0] = s0[2 * l];       g[1] = s0[2 * l + 1];                         \
            g[2] = s0[2 * (l + 64)]; g[3] = s0[2 * (l + 64) + 1];                 \
            g[4] = s1[2 * l];       g[5] = s1[2 * l + 1];                         \
            g[6] = s1[2 * (l + 64)]; g[7] = s1[2 * (l + 64) + 1];                 \
        }
    #define WRITE8(g, pp)                                                         \
        {                                                                         \
            unsigned short* d0 = &ztb[(pp)][(8 + 2 * w) * RPB];                   \
            unsigned short* d1 = &ztb[(pp)][(9 + 2 * w) * RPB];                   \
            *(short8*)(d0 + l * 8) = cvt8(g[0], g[1]);                            \
            *(short8*)(d0 + (l + 64) * 8) = cvt8(g[2], g[3]);                     \
            *(short8*)(d1 + l * 8) = cvt8(g[4], g[5]);                            \
            *(short8*)(d1 + (l + 64) * 8) = cvt8(g[6], g[7]);                     \
        }

    // prologue: stage tile 0 into buffer 0
    ISSUE4(ga, 0, 0)  WRITE4(ga, 0, 0)
    ISSUE4(gb, 0, 4)  WRITE4(gb, 0, 4)
    ISSUE8(gc, 0)     WRITE8(gc, 0)
    __syncthreads();   // tile 0 resident + mlds visible

    for (int it = 0; it < NT; it++) {
        int p = it & 1;
        bool nx = (it + 1 < NT);
        if (nx) ISSUE4(ga, it + 1, 0)      // HBM latency hides under scores

        // --- scores: full d per wave, B-frags read directly as bf16 ---
        f32x4 a0 = {0.f,0.f,0.f,0.f}, a1 = {0.f,0.f,0.f,0.f};
        f32x4 a2 = {0.f,0.f,0.f,0.f}, a3 = {0.f,0.f,0.f,0.f};
        const unsigned short* brow = &ztb[p][frow * RPB + fquad * 8];
        #pragma unroll
        for (int i = 0; i < 32; i += 4) {
            short8 b0 = *(const short8*)(brow + (i + 0) * 32);
            short8 b1 = *(const short8*)(brow + (i + 1) * 32);
            short8 b2 = *(const short8*)(brow + (i + 2) * 32);
            short8 b3 = *(const short8*)(brow + (i + 3) * 32);
            a0 = __builtin_amdgcn_mfma_f32_16x16x32_bf16(rA[i + 0], b0, a0, 0, 0, 0);
            a1 = __builtin_amdgcn_mfma_f32_16x16x32_bf16(rA[i + 1], b1, a1, 0, 0, 0);
            a2 = __builtin_amdgcn_mfma_f32_16x16x32_bf16(rA[i + 2], b2, a2, 0, 0, 0);
            a3 = __builtin_amdgcn_mfma_f32_16x16x32_bf16(rA[i + 3], b3, a3, 0, 0, 0);
        }
        f32x4 acc = a0 + a1 + a2 + a3;   // C[h=fquad*4+r][n=frow]

        if (nx) { WRITE4(ga, p ^ 1, 0)  ISSUE4(gb, it + 1, 4) }

        // --- e = masked exp(s); scores O(0.1) so no max-subtraction ---
        {
            int gn = n0 + it * 16 + frow;
            bool valid = (mlds[it * 16 + frow] != 0) || (gn == 0 && anyb == 0);
            float e0 = valid ? __expf(acc[0]) : 0.f;
            float e1 = valid ? __expf(acc[1]) : 0.f;
            float e2 = valid ? __expf(acc[2]) : 0.f;
            float e3 = valid ? __expf(acc[3]) : 0.f;
            l4[0] += e0; l4[1] += e1; l4[2] += e2; l4[3] += e3;
            // Ew[w][n][h] — wave-private, no cross-wave barrier needed
            *(float4*)&Ew[w][frow][fquad * 4] = make_float4(e0, e1, e2, e3);
        }

        // --- ctx: wave w owns d in [256w,+256); lane covers d = 256w+4l..+4 ---
        const unsigned short* zcol = &ztb[p][w * 256 + 4 * l];
        #define CTXROW(r)                                                         \
            {                                                                     \
                ushort4 u = *(const ushort4*)(zcol + (r) * RPB);                  \
                float zx = bflo(u.x), zy = bflo(u.y);                             \
                float zz = bflo(u.z), zw = bflo(u.w);                             \
                const float4* er4 = (const float4*)&Ew[w][(r)][0];                \
                float4 e0 = er4[0], e1 = er4[1], e2 = er4[2], e3 = er4[3];        \
                ctx[0].x  += e0.x * zx; ctx[0].y  += e0.x * zy; ctx[0].z  += e0.x * zz; ctx[0].w  += e0.x * zw; \
                ctx[1].x  += e0.y * zx; ctx[1].y  += e0.y * zy; ctx[1].z  += e0.y * zz; ctx[1].w  += e0.y * zw; \
                ctx[2].x  += e0.z * zx; ctx[2].y  += e0.z * zy; ctx[2].z  += e0.z * zz; ctx[2].w  += e0.z * zw; \
                ctx[3].x  += e0.w * zx; ctx[3].y  += e0.w * zy; ctx[3].z  += e0.w * zz; ctx[3].w  += e0.w * zw; \
                ctx[4].x  += e1.x * zx; ctx[4].y  += e1.x * zy; ctx[4].z  += e1.x * zz; ctx[4].w  += e1.x * zw; \
                ctx[5].x  += e1.y * zx; ctx[5].y  += e1.y * zy; ctx[5].z  += e1.y * zz; ctx[5].w  += e1.y * zw; \
                ctx[6].x  += e1.z * zx; ctx[6].y  += e1.z * zy; ctx[6].z  += e1.z * zz; ctx[6].w  += e1.z * zw; \
                ctx[7].x  += e1.w * zx; ctx[7].y  += e1.w * zy; ctx[7].z  += e1.w * zz; ctx[7].w  += e1.w * zw; \
                ctx[8].x  += e2.x * zx; ctx[8].y  += e2.x * zy; ctx[8].z  += e2.x * zz; ctx[8].w  += e2.x * zw; \
                ctx[9].x  += e2.y * zx; ctx[9].y  += e2.y * zy; ctx[9].z  += e2.y * zz; ctx[9].w  += e2.y * zw; \
                ctx[10].x += e2.z * zx; ctx[10].y += e2.z * zy; ctx[10].z += e2.z * zz; ctx[10].w += e2.z * zw; \
                ctx[11].x += e2.w * zx; ctx[11].y += e2.w * zy; ctx[11].z += e2.w * zz; ctx[11].w += e2.w * zw; \
                ctx[12].x += e3.x * zx; ctx[12].y += e3.x * zy; ctx[12].z += e3.x * zz; ctx[12].w += e3.x * zw; \
                ctx[13].x += e3.y * zx; ctx[13].y += e3.y * zy; ctx[13].z += e3.y * zz; ctx[13].w += e3.y * zw; \
                ctx[14].x += e3.z * zx; ctx[14].y += e3.z * zy; ctx[14].z += e3.z * zz; ctx[14].w += e3.z * zw; \
                ctx[15].x += e3.w * zx; ctx[15].y += e3.w * zy; ctx[15].z += e3.w * zz; ctx[15].w += e3.w * zw; \
            }
        #pragma unroll
        for (int r = 0; r < 8; r++) CTXROW(r)
        if (nx) { WRITE4(gb, p ^ 1, 4)  ISSUE8(gc, it + 1) }
        #pragma unroll
        for (int r = 8; r < 16; r++) CTXROW(r)
        if (nx) WRITE8(gc, p ^ 1)
        __syncthreads();   // writes to p^1 visible; all reads of p done
    }

    // --- epilogue: bf16 partials + f32 l ---
    {
        unsigned short* pp = part + (size_t)bx * 16 * 1024 + w * 256 + 4 * l;
        #pragma unroll
        for (int h = 0; h < 16; h++) {
            ushort4 o;
            o.x = f2bf(ctx[h].x); o.y = f2bf(ctx[h].y);
            o.z = f2bf(ctx[h].z); o.w = f2bf(ctx[h].w);
            *(ushort4*)(pp + h * 1024) = o;
        }
    }
    if (w == 0) {
        #pragma unroll
        for (int r = 0; r < 4; r++) {
            float v = l4[r];
            v += __shfl_xor(v, 1, 64);
            v += __shfl_xor(v, 2, 64);
            v += __shfl_xor(v, 4, 64);
            v += __shfl_xor(v, 8, 64);
            if (frow == 0) l_part[bx * 16 + fquad * 4 + r] = v;
        }
    }
}

// ---------------------------------------------------------------------------
// gemv_wv_k: block (b,h). Phase A: vlds = (sum_c part[b][c][h][:]) / L[b][h].
// Phase B: pooled[b][64h+j] = w_v[64h+j,:].vlds + b_v (4-acc ILP GEMV).
// ---------------------------------------------------------------------------
__global__ __launch_bounds__(256) void gemv_wv_k(const unsigned short* __restrict__ part,
        const float* __restrict__ l_part, const float* __restrict__ w_v,
        const float* __restrict__ b_v, float* __restrict__ pooled) {
    __shared__ __align__(16) float vlds[1024];
    int bx = blockIdx.x, t = threadIdx.x;
    int b = bx >> 4, h = bx & 15;
    float L = 0.f;
    #pragma unroll
    for (int cc = 0; cc < 16; cc++) L += l_part[(b * 16 + cc) * 16 + h];
    float rL = 1.f / L;
    float sx = 0.f, sy = 0.f, sz = 0.f, sw = 0.f;
    #pragma unroll
    for (int cc = 0; cc < 16; cc++) {
        const ushort4* p4 = (const ushort4*)&part[(((size_t)(b * 16 + cc)) * 16 + h) * 1024];
        ushort4 u = p4[t];
        sx += bflo(u.x); sy += bflo(u.y); sz += bflo(u.z); sw += bflo(u.w);
    }
    *(float4*)&vlds[4 * t] = make_float4(sx * rL, sy * rL, sz * rL, sw * rL);
    __syncthreads();
    int w = t >> 6, l = t & 63;
    const float4* v4 = (const float4*)vlds;
    float* orow = pooled + (size_t)b * 1024;
    #pragma unroll
    for (int s0 = 0; s0 < 16; s0 += 4) {
        int jb = h * 64 + w * 16 + s0;
        float a0 = 0.f, a1 = 0.f, a2 = 0.f, a3 = 0.f;
        #pragma unroll
        for (int kk = 0; kk < 4; kk++) {
            float4 v = v4[kk * 64 + l];
            float4 w0 = *(const float4*)&w_v[(size_t)(jb + 0) * 1024 + (kk * 64 + l) * 4];
            float4 w1 = *(const float4*)&w_v[(size_t)(jb + 1) * 1024 + (kk * 64 + l) * 4];
            float4 w2 = *(const float4*)&w_v[(size_t)(jb + 2) * 1024 + (kk * 64 + l) * 4];
            float4 w3 = *(const float4*)&w_v[(size_t)(jb + 3) * 1024 + (kk * 64 + l) * 4];
            a0 += w0.x * v.x + w0.y * v.y + w0.z * v.z + w0.w * v.w;
            a1 += w1.x * v.x + w1.y * v.y + w1.z * v.z + w1.w * v.w;
            a2 += w2.x * v.x + w2.y * v.y + w2.z * v.z + w2.w * v.w;
            a3 += w3.x * v.x + w3.y * v.y + w3.z * v.z + w3.w * v.w;
        }
        #pragma unroll
        for (int m = 32; m >= 1; m >>= 1) {
            a0 += __shfl_xor(a0, m, 64); a1 += __shfl_xor(a1, m, 64);
            a2 += __shfl_xor(a2, m, 64); a3 += __shfl_xor(a3, m, 64);
        }
        if (l == 0) {
            orow[jb + 0] = a0 + b_v[jb + 0];
            orow[jb + 1] = a1 + b_v[jb + 1];
            orow[jb + 2] = a2 + b_v[jb + 2];
            orow[jb + 3] = a3 + b_v[jb + 3];
        }
    }
}

// ---------------------------------------------------------------------------
// gemv_wo_k: block (b,q). out[b][64q+j] = w_o[64q+j,:].pooled[b] + b_o
// ---------------------------------------------------------------------------
__global__ __launch_bounds__(256) void gemv_wo_k(const float* __restrict__ pooled,
        const float* __restrict__ w_o, const float* __restrict__ b_o,
        float* __restrict__ out) {
    __shared__ __align__(16) float vlds[1024];
    int bx = blockIdx.x, t = threadIdx.x;
    int b = bx >> 4, q = bx & 15;
    *(float4*)&vlds[4 * t] = *(const float4*)&pooled[(size_t)b * 1024 + 4 * t];
    __syncthreads();
    int w = t >> 6, l = t & 63;
    const float4* v4 = (const float4*)vlds;
    float* orow = out + (size_t)b * 1024;
    #pragma unroll
    for (int s0 = 0; s0 < 16; s0 += 4) {
        int jb = q * 64 + w * 16 + s0;
        float a0 = 0.f, a1 = 0.f, a2 = 0.f, a3 = 0.f;
        #pragma unroll
        for (int kk = 0; kk < 4; kk++) {
            float4 v = v4[kk * 64 + l];
            float4 w0 = *(const float4*)&w_o[(size_t)(jb + 0) * 1024 + (kk * 64 + l) * 4];
            float4 w1 = *(const float4*)&w_o[(size_t)(jb + 1) * 1024 + (kk * 64 + l) * 4];
            float4 w2 = *(const float4*)&w_o[(size_t)(jb + 2) * 1024 + (kk * 64 + l) * 4];
            float4 w3 = *(const float4*)&w_o[(size_t)(jb + 3) * 1024 + (kk * 64 + l) * 4];
            a0 += w0.x * v.x + w0.y * v.y + w0.z * v.z + w0.w * v.w;
            a1 += w1.x * v.x + w1.y * v.y + w1.z * v.z + w1.w * v.w;
            a2 += w2.x * v.x + w2.y * v.y + w2.z * v.z + w2.w * v.w;
            a3 += w3.x * v.x + w3.y * v.y + w3.z * v.z + w3.w * v.w;
        }
        #pragma unroll
        for (int m = 32; m >= 1; m >>= 1) {
            a0 += __shfl_xor(a0, m, 64); a1 += __shfl_xor(a1, m, 64);
            a2 += __shfl_xor(a2, m, 64); a3 += __shfl_xor(a3, m, 64);
        }
        if (l == 0) {
            orow[jb + 0] = a0 + b_o[jb + 0];
            orow[jb + 1] = a1 + b_o[jb + 1];
            orow[jb + 2] = a2 + b_o[jb + 2];
            orow[jb + 3] = a3 + b_o[jb + 3];
        }
    }
}

// ---------------------------------------------------------------------------
extern "C" void kernel_launch(void* const* d_in, const int* in_sizes, int n_in,
                              void* d_out, int out_size, void* d_ws, size_t ws_size,
                              hipStream_t stream) {
    const float* z     = (const float*)d_in[0];
    const int*   mask  = (const int*)d_in[1];
    const float* query = (const float*)d_in[2];
    const float* w_q   = (const float*)d_in[3];
    const float* w_k   = (const float*)d_in[4];
    const float* w_v   = (const float*)d_in[5];
    const float* b_q   = (const float*)d_in[6];
    // d_in[7] = b_k: constant per (b,h) over n -> cancels in softmax
    const float* b_v   = (const float*)d_in[8];
    const float* w_o   = (const float*)d_in[9];
    const float* b_o   = (const float*)d_in[10];
    float* out = (float*)d_out;

    char* ws = (char*)d_ws;
    unsigned short* rAf    = (unsigned short*)(ws + 0);       // 32 KB
    int*            any_ws = (int*)(ws + 32768);              // 128 B
    float*          l_part = (float*)(ws + 36864);            // 32 KB
    float*          pooled = (float*)(ws + 131072);           // 128 KB
    unsigned short* part   = (unsigned short*)(ws + 1048576); // 16 MB

    prep_k<<<96, 256, 0, stream>>>(query, w_q, b_q, w_k, mask, rAf, any_ws);
    main_k<<<512, 256, 0, stream>>>(z, mask, any_ws, rAf, part, l_part);
    gemv_wv_k<<<512, 256, 0, stream>>>(part, l_part, w_v, b_v, pooled);
    gemv_wo_k<<<512, 256, 0, stream>>>(pooled, w_o, b_o, out);
}

// Round 3
// 494.420 us; speedup vs baseline: 1.8244x; 1.8244x over previous
//
#include <hip/hip_runtime.h>
#include <hip/hip_bf16.h>
#include <stdint.h>

#define B_ 32
#define N_ 2048
#define D_ 1024
#define H_ 16

#define NT 16          // 16-row tiles per block (256 rows/block)
#define RPAD 1028      // f32 row stride in LDS (+4 pad)

typedef __attribute__((ext_vector_type(8))) short short8;
typedef __attribute__((ext_vector_type(4))) float f32x4;

__device__ __forceinline__ unsigned short f2bf(float x) {
    unsigned u = __float_as_uint(x);
    u += 0x7FFFu + ((u >> 16) & 1u);   // RNE
    return (unsigned short)(u >> 16);
}
__device__ __forceinline__ float bflo(unsigned u) { return __uint_as_float(u << 16); }

// pack 8 f32 -> short8 bf16 (RNE packed cvt)
__device__ __forceinline__ short8 cvt8(float4 a, float4 b) {
    union { __hip_bfloat162 h[4]; short8 s; } u;
    u.h[0] = __float22bfloat162_rn(make_float2(a.x, a.y));
    u.h[1] = __float22bfloat162_rn(make_float2(a.z, a.w));
    u.h[2] = __float22bfloat162_rn(make_float2(b.x, b.y));
    u.h[3] = __float22bfloat162_rn(make_float2(b.z, b.w));
    return u.s;
}

// ---------------------------------------------------------------------------
// prep_k (fused): blocks 0..63 (h=bx>>2, dg=bx&3):
//   phase 1: q_h[j] = query . w_q[64h+j,:] + b_q[64h+j]      (j in [0,64))
//   phase 2: R[h][d] = 0.125 * sum_j q_h[j] w_k[64h+j][d], d in [256dg,+256),
//            packed directly as bf16 MFMA A-fragments.
// blocks 64..95: any_ws[b] = OR over mask row (b = bx-64).
// ---------------------------------------------------------------------------
__global__ __launch_bounds__(256) void prep_k(const float* __restrict__ query,
        const float* __restrict__ w_q, const float* __restrict__ b_q,
        const float* __restrict__ w_k, const int* __restrict__ mask,
        unsigned short* __restrict__ rAf, int* __restrict__ any_ws) {
    __shared__ __align__(16) float qv[1024];
    __shared__ float qp[64][5];
    __shared__ float qh[64];
    __shared__ int wf[4];
    int bx = blockIdx.x, t = threadIdx.x;
    if (bx < 64) {
        int h = bx >> 2, dg = bx & 3;
        *(float4*)&qv[4 * t] = *(const float4*)&query[4 * t];
        __syncthreads();
        // ---- phase 1: q row (64 outputs, 4 threads per output) ----
        {
            int j = t >> 2, sub = t & 3;
            const float4* wq4 = (const float4*)(w_q + (size_t)(h * 64 + j) * 1024);
            const float4* qv4 = (const float4*)qv;
            float a = 0.f;
            #pragma unroll 8
            for (int kk = 0; kk < 64; kk++) {
                float4 wv = wq4[sub * 64 + kk];
                float4 vv = qv4[sub * 64 + kk];
                a += wv.x * vv.x + wv.y * vv.y + wv.z * vv.z + wv.w * vv.w;
            }
            qp[j][sub] = a;
        }
        __syncthreads();
        if (t < 64)
            qh[t] = qp[t][0] + qp[t][1] + qp[t][2] + qp[t][3] + b_q[h * 64 + t];
        __syncthreads();
        // ---- phase 2: R slice, pack A-fragment ----
        int d = dg * 256 + t;
        float acc = 0.f;
        #pragma unroll 8
        for (int j = 0; j < 64; j++)
            acc += qh[j] * w_k[(size_t)(h * 64 + j) * 1024 + d];
        acc *= 0.125f;                       // 1/sqrt(64) folded into R
        int i = d >> 5, fq = (d >> 3) & 3, jj = d & 7;
        int lane = (fq << 4) | h;            // A[m=lane&15][k=(lane>>4)*8+j]
        rAf[(size_t)(i * 64 + lane) * 8 + jj] = f2bf(acc);
    } else {
        int b = bx - 64;
        int v = 0;
        for (int k = 0; k < 8; k++) v |= mask[b * N_ + k * 256 + t];
        unsigned long long bal = __ballot(v != 0);
        int w = t >> 6;
        if ((t & 63) == 0) wf[w] = (bal != 0ull) ? 1 : 0;
        __syncthreads();
        if (t == 0) any_ws[b] = wf[0] | wf[1] | wf[2] | wf[3];
    }
}

// ---------------------------------------------------------------------------
// main_k v3: grid 256 (b=bx>>3, chunk c=bx&7 -> 256 rows, 16 x 16-row tiles),
// but 512 THREADS (8 waves = 2 waves/SIMD at 1 block/CU) for latency hiding.
// Structure identical to the proven 161us r1 kernel: f32 z tile staged via
// global_load_lds (zero staging VGPRs), double-buffered, ONE barrier/tile.
// All 8 waves compute full-d scores redundantly (MFMA util was 2% - free);
// ctx splits d 8 ways -> ctx is float2[16] = 32 VGPRs (was 64). rA[32]=128.
// Total ~190 VGPRs < 256 cap (launch_bounds(512,2)) -> no spill.
// Mask row preloaded to LDS (kills per-tile unhidden global-load stalls).
// ---------------------------------------------------------------------------
__global__ __launch_bounds__(512, 2) void main_k(const float* __restrict__ z,
        const int* __restrict__ mask, const int* __restrict__ any_ws,
        const unsigned short* __restrict__ rAf,
        unsigned short* __restrict__ part, float* __restrict__ l_part) {
    __shared__ __align__(16) float zt[2][16 * RPAD];   // 131,584 B
    __shared__ __align__(16) float Ew[8][16][16];      // 8,192 B (wave-private)
    __shared__ int mlds[256];                          // 1,024 B
    int bx = blockIdx.x, t = threadIdx.x;
    int b = bx >> 3, c = bx & 7;
    int n0 = c * 256;
    int w = t >> 6, l = t & 63;
    int frow = l & 15, fquad = l >> 4;
    int anyb = any_ws[b];

    // preload all 32 A-fragments (128 VGPRs; same values in every wave)
    short8 rA[32];
    {
        const short8* rA8 = (const short8*)rAf;
        #pragma unroll
        for (int i = 0; i < 32; i++) rA[i] = rA8[i * 64 + l];
    }
    const float* zb = z + (size_t)b * N_ * D_ + (size_t)n0 * D_;

    if (t < 256) mlds[t] = mask[b * N_ + n0 + t];

    float2 ctx[16];
    #pragma unroll
    for (int h = 0; h < 16; h++) ctx[h] = make_float2(0.f, 0.f);
    float l4[4] = {0.f, 0.f, 0.f, 0.f};

    // async stage one 16-row tile: wave w loads rows 2w and 2w+1 (4 x 1KB each).
    // LDS dest is wave-uniform base + lane*16B (HW rule).
    #define STAGE(p, tile)                                                        \
        {                                                                         \
            _Pragma("unroll")                                                     \
            for (int rr = 0; rr < 2; rr++) {                                      \
                int row = 2 * w + rr;                                             \
                const float* gsrc = zb + (size_t)(tile) * 16 * D_ +               \
                                    (size_t)row * D_ + l * 4;                     \
                float* ldst = &zt[(p)][row * RPAD];                               \
                _Pragma("unroll")                                                 \
                for (int q = 0; q < 4; q++) {                                     \
                    __builtin_amdgcn_global_load_lds(                             \
                        (const __attribute__((address_space(1))) unsigned int*)   \
                            (gsrc + q * 256),                                     \
                        (__attribute__((address_space(3))) unsigned int*)         \
                            (ldst + q * 256),                                     \
                        16, 0, 0);                                                \
                }                                                                 \
            }                                                                     \
        }

    STAGE(0, 0)
    __syncthreads();   // tile 0 resident + mlds visible

    for (int it = 0; it < NT; it++) {
        int p = it & 1;
        if (it + 1 < NT) STAGE(p ^ 1, it + 1)   // overlaps this tile's compute

        // --- scores: full d per wave, 4 independent MFMA accumulators ---
        f32x4 a0 = {0.f,0.f,0.f,0.f}, a1 = {0.f,0.f,0.f,0.f};
        f32x4 a2 = {0.f,0.f,0.f,0.f}, a3 = {0.f,0.f,0.f,0.f};
        const float* brow = &zt[p][frow * RPAD + fquad * 8];
        #pragma unroll
        for (int i = 0; i < 32; i += 4) {
            float4 z00 = *(const float4*)(brow + (i + 0) * 32);
            float4 z01 = *(const float4*)(brow + (i + 0) * 32 + 4);
            float4 z10 = *(const float4*)(brow + (i + 1) * 32);
            float4 z11 = *(const float4*)(brow + (i + 1) * 32 + 4);
            float4 z20 = *(const float4*)(brow + (i + 2) * 32);
            float4 z21 = *(const float4*)(brow + (i + 2) * 32 + 4);
            float4 z30 = *(const float4*)(brow + (i + 3) * 32);
            float4 z31 = *(const float4*)(brow + (i + 3) * 32 + 4);
            a0 = __builtin_amdgcn_mfma_f32_16x16x32_bf16(rA[i + 0], cvt8(z00, z01), a0, 0, 0, 0);
            a1 = __builtin_amdgcn_mfma_f32_16x16x32_bf16(rA[i + 1], cvt8(z10, z11), a1, 0, 0, 0);
            a2 = __builtin_amdgcn_mfma_f32_16x16x32_bf16(rA[i + 2], cvt8(z20, z21), a2, 0, 0, 0);
            a3 = __builtin_amdgcn_mfma_f32_16x16x32_bf16(rA[i + 3], cvt8(z30, z31), a3, 0, 0, 0);
        }
        f32x4 acc = a0 + a1 + a2 + a3;   // C[h=fquad*4+r][n=frow]

        // --- e = masked exp(s); scores O(0.1) so no max-subtraction ---
        {
            int gn = n0 + it * 16 + frow;
            bool valid = (mlds[it * 16 + frow] != 0) || (gn == 0 && anyb == 0);
            float e0 = valid ? __expf(acc[0]) : 0.f;
            float e1 = valid ? __expf(acc[1]) : 0.f;
            float e2 = valid ? __expf(acc[2]) : 0.f;
            float e3 = valid ? __expf(acc[3]) : 0.f;
            l4[0] += e0; l4[1] += e1; l4[2] += e2; l4[3] += e3;
            // Ew[w][n][h] — wave-private copy, no cross-wave barrier needed
            *(float4*)&Ew[w][frow][fquad * 4] = make_float4(e0, e1, e2, e3);
        }

        // --- ctx: wave w owns d in [128w,+128); lane covers d = 128w+2l..+1 ---
        {
            const float* zcol = &zt[p][w * 128 + 2 * l];
            #pragma unroll 4
            for (int r = 0; r < 16; r++) {
                float2 zr = *(const float2*)(zcol + r * RPAD);
                const float4* er4 = (const float4*)&Ew[w][r][0];
                float4 e0 = er4[0], e1 = er4[1], e2 = er4[2], e3 = er4[3];
                ctx[0].x  += e0.x * zr.x; ctx[0].y  += e0.x * zr.y;
                ctx[1].x  += e0.y * zr.x; ctx[1].y  += e0.y * zr.y;
                ctx[2].x  += e0.z * zr.x; ctx[2].y  += e0.z * zr.y;
                ctx[3].x  += e0.w * zr.x; ctx[3].y  += e0.w * zr.y;
                ctx[4].x  += e1.x * zr.x; ctx[4].y  += e1.x * zr.y;
                ctx[5].x  += e1.y * zr.x; ctx[5].y  += e1.y * zr.y;
                ctx[6].x  += e1.z * zr.x; ctx[6].y  += e1.z * zr.y;
                ctx[7].x  += e1.w * zr.x; ctx[7].y  += e1.w * zr.y;
                ctx[8].x  += e2.x * zr.x; ctx[8].y  += e2.x * zr.y;
                ctx[9].x  += e2.y * zr.x; ctx[9].y  += e2.y * zr.y;
                ctx[10].x += e2.z * zr.x; ctx[10].y += e2.z * zr.y;
                ctx[11].x += e2.w * zr.x; ctx[11].y += e2.w * zr.y;
                ctx[12].x += e3.x * zr.x; ctx[12].y += e3.x * zr.y;
                ctx[13].x += e3.y * zr.x; ctx[13].y += e3.y * zr.y;
                ctx[14].x += e3.z * zr.x; ctx[14].y += e3.z * zr.y;
                ctx[15].x += e3.w * zr.x; ctx[15].y += e3.w * zr.y;
            }
        }
        __syncthreads();   // single per-tile barrier: drains prefetch
    }

    // --- epilogue: bf16 partials + f32 l ---
    {
        unsigned short* pp = part + (size_t)bx * 16 * 1024 + w * 128 + 2 * l;
        #pragma unroll
        for (int h = 0; h < 16; h++) {
            ushort2 o;
            o.x = f2bf(ctx[h].x); o.y = f2bf(ctx[h].y);
            *(ushort2*)(pp + h * 1024) = o;
        }
    }
    if (w == 0) {
        #pragma unroll
        for (int r = 0; r < 4; r++) {
            float v = l4[r];
            v += __shfl_xor(v, 1, 64);
            v += __shfl_xor(v, 2, 64);
            v += __shfl_xor(v, 4, 64);
            v += __shfl_xor(v, 8, 64);
            if (frow == 0) l_part[bx * 16 + fquad * 4 + r] = v;
        }
    }
}

// ---------------------------------------------------------------------------
// gemv_wv_k: block (b,h). Phase A: vlds = (sum_c part[b][c][h][:]) / L[b][h].
// Phase B: pooled[b][64h+j] = w_v[64h+j,:].vlds + b_v (4-acc ILP GEMV).
// ---------------------------------------------------------------------------
__global__ __launch_bounds__(256) void gemv_wv_k(const unsigned short* __restrict__ part,
        const float* __restrict__ l_part, const float* __restrict__ w_v,
        const float* __restrict__ b_v, float* __restrict__ pooled) {
    __shared__ __align__(16) float vlds[1024];
    int bx = blockIdx.x, t = threadIdx.x;
    int b = bx >> 4, h = bx & 15;
    float L = 0.f;
    #pragma unroll
    for (int cc = 0; cc < 8; cc++) L += l_part[(b * 8 + cc) * 16 + h];
    float rL = 1.f / L;
    float sx = 0.f, sy = 0.f, sz = 0.f, sw = 0.f;
    #pragma unroll
    for (int cc = 0; cc < 8; cc++) {
        const ushort4* p4 = (const ushort4*)&part[(((size_t)(b * 8 + cc)) * 16 + h) * 1024];
        ushort4 u = p4[t];
        sx += bflo(u.x); sy += bflo(u.y); sz += bflo(u.z); sw += bflo(u.w);
    }
    *(float4*)&vlds[4 * t] = make_float4(sx * rL, sy * rL, sz * rL, sw * rL);
    __syncthreads();
    int w = t >> 6, l = t & 63;
    const float4* v4 = (const float4*)vlds;
    float* orow = pooled + (size_t)b * 1024;
    #pragma unroll
    for (int s0 = 0; s0 < 16; s0 += 4) {
        int jb = h * 64 + w * 16 + s0;
        float a0 = 0.f, a1 = 0.f, a2 = 0.f, a3 = 0.f;
        #pragma unroll
        for (int kk = 0; kk < 4; kk++) {
            float4 v = v4[kk * 64 + l];
            float4 w0 = *(const float4*)&w_v[(size_t)(jb + 0) * 1024 + (kk * 64 + l) * 4];
            float4 w1 = *(const float4*)&w_v[(size_t)(jb + 1) * 1024 + (kk * 64 + l) * 4];
            float4 w2 = *(const float4*)&w_v[(size_t)(jb + 2) * 1024 + (kk * 64 + l) * 4];
            float4 w3 = *(const float4*)&w_v[(size_t)(jb + 3) * 1024 + (kk * 64 + l) * 4];
            a0 += w0.x * v.x + w0.y * v.y + w0.z * v.z + w0.w * v.w;
            a1 += w1.x * v.x + w1.y * v.y + w1.z * v.z + w1.w * v.w;
            a2 += w2.x * v.x + w2.y * v.y + w2.z * v.z + w2.w * v.w;
            a3 += w3.x * v.x + w3.y * v.y + w3.z * v.z + w3.w * v.w;
        }
        #pragma unroll
        for (int m = 32; m >= 1; m >>= 1) {
            a0 += __shfl_xor(a0, m, 64); a1 += __shfl_xor(a1, m, 64);
            a2 += __shfl_xor(a2, m, 64); a3 += __shfl_xor(a3, m, 64);
        }
        if (l == 0) {
            orow[jb + 0] = a0 + b_v[jb + 0];
            orow[jb + 1] = a1 + b_v[jb + 1];
            orow[jb + 2] = a2 + b_v[jb + 2];
            orow[jb + 3] = a3 + b_v[jb + 3];
        }
    }
}

// ---------------------------------------------------------------------------
// gemv_wo_k: block (b,q). out[b][64q+j] = w_o[64q+j,:].pooled[b] + b_o
// ---------------------------------------------------------------------------
__global__ __launch_bounds__(256) void gemv_wo_k(const float* __restrict__ pooled,
        const float* __restrict__ w_o, const float* __restrict__ b_o,
        float* __restrict__ out) {
    __shared__ __align__(16) float vlds[1024];
    int bx = blockIdx.x, t = threadIdx.x;
    int b = bx >> 4, q = bx & 15;
    *(float4*)&vlds[4 * t] = *(const float4*)&pooled[(size_t)b * 1024 + 4 * t];
    __syncthreads();
    int w = t >> 6, l = t & 63;
    const float4* v4 = (const float4*)vlds;
    float* orow = out + (size_t)b * 1024;
    #pragma unroll
    for (int s0 = 0; s0 < 16; s0 += 4) {
        int jb = q * 64 + w * 16 + s0;
        float a0 = 0.f, a1 = 0.f, a2 = 0.f, a3 = 0.f;
        #pragma unroll
        for (int kk = 0; kk < 4; kk++) {
            float4 v = v4[kk * 64 + l];
            float4 w0 = *(const float4*)&w_o[(size_t)(jb + 0) * 1024 + (kk * 64 + l) * 4];
            float4 w1 = *(const float4*)&w_o[(size_t)(jb + 1) * 1024 + (kk * 64 + l) * 4];
            float4 w2 = *(const float4*)&w_o[(size_t)(jb + 2) * 1024 + (kk * 64 + l) * 4];
            float4 w3 = *(const float4*)&w_o[(size_t)(jb + 3) * 1024 + (kk * 64 + l) * 4];
            a0 += w0.x * v.x + w0.y * v.y + w0.z * v.z + w0.w * v.w;
            a1 += w1.x * v.x + w1.y * v.y + w1.z * v.z + w1.w * v.w;
            a2 += w2.x * v.x + w2.y * v.y + w2.z * v.z + w2.w * v.w;
            a3 += w3.x * v.x + w3.y * v.y + w3.z * v.z + w3.w * v.w;
        }
        #pragma unroll
        for (int m = 32; m >= 1; m >>= 1) {
            a0 += __shfl_xor(a0, m, 64); a1 += __shfl_xor(a1, m, 64);
            a2 += __shfl_xor(a2, m, 64); a3 += __shfl_xor(a3, m, 64);
        }
        if (l == 0) {
            orow[jb + 0] = a0 + b_o[jb + 0];
            orow[jb + 1] = a1 + b_o[jb + 1];
            orow[jb + 2] = a2 + b_o[jb + 2];
            orow[jb + 3] = a3 + b_o[jb + 3];
        }
    }
}

// ---------------------------------------------------------------------------
extern "C" void kernel_launch(void* const* d_in, const int* in_sizes, int n_in,
                              void* d_out, int out_size, void* d_ws, size_t ws_size,
                              hipStream_t stream) {
    const float* z     = (const float*)d_in[0];
    const int*   mask  = (const int*)d_in[1];
    const float* query = (const float*)d_in[2];
    const float* w_q   = (const float*)d_in[3];
    const float* w_k   = (const float*)d_in[4];
    const float* w_v   = (const float*)d_in[5];
    const float* b_q   = (const float*)d_in[6];
    // d_in[7] = b_k: constant per (b,h) over n -> cancels in softmax
    const float* b_v   = (const float*)d_in[8];
    const float* w_o   = (const float*)d_in[9];
    const float* b_o   = (const float*)d_in[10];
    float* out = (float*)d_out;

    char* ws = (char*)d_ws;
    unsigned short* rAf    = (unsigned short*)(ws + 0);       // 32 KB
    int*            any_ws = (int*)(ws + 32768);              // 128 B
    float*          l_part = (float*)(ws + 40960);            // 16 KB
    float*          pooled = (float*)(ws + 65536);            // 128 KB
    unsigned short* part   = (unsigned short*)(ws + 1048576); // 8 MB

    prep_k<<<96, 256, 0, stream>>>(query, w_q, b_q, w_k, mask, rAf, any_ws);
    main_k<<<256, 512, 0, stream>>>(z, mask, any_ws, rAf, part, l_part);
    gemv_wv_k<<<512, 256, 0, stream>>>(part, l_part, w_v, b_v, pooled);
    gemv_wo_k<<<512, 256, 0, stream>>>(pooled, w_o, b_o, out);
}

// Round 4
// 423.649 us; speedup vs baseline: 2.1292x; 1.1671x over previous
//
#include <hip/hip_runtime.h>
#include <hip/hip_bf16.h>
#include <stdint.h>

#define B_ 32
#define N_ 2048
#define D_ 1024
#define H_ 16

#define NT 16          // 16-row tiles per block (256 rows/block)
#define RPAD 1028      // f32 row stride in LDS (+4 pad)

typedef __attribute__((ext_vector_type(8))) short short8;
typedef __attribute__((ext_vector_type(4))) float f32x4;

__device__ __forceinline__ unsigned short f2bf(float x) {
    unsigned u = __float_as_uint(x);
    u += 0x7FFFu + ((u >> 16) & 1u);   // RNE
    return (unsigned short)(u >> 16);
}
__device__ __forceinline__ float bflo(unsigned u) { return __uint_as_float(u << 16); }

// pack 8 f32 -> short8 bf16 (RNE packed cvt)
__device__ __forceinline__ short8 cvt8(float4 a, float4 b) {
    union { __hip_bfloat162 h[4]; short8 s; } u;
    u.h[0] = __float22bfloat162_rn(make_float2(a.x, a.y));
    u.h[1] = __float22bfloat162_rn(make_float2(a.z, a.w));
    u.h[2] = __float22bfloat162_rn(make_float2(b.x, b.y));
    u.h[3] = __float22bfloat162_rn(make_float2(b.z, b.w));
    return u.s;
}

// ---------------------------------------------------------------------------
// prep_k (fused): blocks 0..63 (h=bx>>2, dg=bx&3):
//   phase 1: q_h[j] = query . w_q[64h+j,:] + b_q[64h+j]      (j in [0,64))
//   phase 2: R[h][d] = 0.125 * sum_j q_h[j] w_k[64h+j][d], d in [256dg,+256),
//            packed directly as bf16 MFMA A-fragments.
// blocks 64..95: any_ws[b] = OR over mask row (b = bx-64).
// ---------------------------------------------------------------------------
__global__ __launch_bounds__(256) void prep_k(const float* __restrict__ query,
        const float* __restrict__ w_q, const float* __restrict__ b_q,
        const float* __restrict__ w_k, const int* __restrict__ mask,
        unsigned short* __restrict__ rAf, int* __restrict__ any_ws) {
    __shared__ __align__(16) float qv[1024];
    __shared__ float qp[64][5];
    __shared__ float qh[64];
    __shared__ int wf[4];
    int bx = blockIdx.x, t = threadIdx.x;
    if (bx < 64) {
        int h = bx >> 2, dg = bx & 3;
        *(float4*)&qv[4 * t] = *(const float4*)&query[4 * t];
        __syncthreads();
        // ---- phase 1: q row (64 outputs, 4 threads per output) ----
        {
            int j = t >> 2, sub = t & 3;
            const float4* wq4 = (const float4*)(w_q + (size_t)(h * 64 + j) * 1024);
            const float4* qv4 = (const float4*)qv;
            float a = 0.f;
            #pragma unroll 8
            for (int kk = 0; kk < 64; kk++) {
                float4 wv = wq4[sub * 64 + kk];
                float4 vv = qv4[sub * 64 + kk];
                a += wv.x * vv.x + wv.y * vv.y + wv.z * vv.z + wv.w * vv.w;
            }
            qp[j][sub] = a;
        }
        __syncthreads();
        if (t < 64)
            qh[t] = qp[t][0] + qp[t][1] + qp[t][2] + qp[t][3] + b_q[h * 64 + t];
        __syncthreads();
        // ---- phase 2: R slice, pack A-fragment ----
        int d = dg * 256 + t;
        float acc = 0.f;
        #pragma unroll 8
        for (int j = 0; j < 64; j++)
            acc += qh[j] * w_k[(size_t)(h * 64 + j) * 1024 + d];
        acc *= 0.125f;                       // 1/sqrt(64) folded into R
        int i = d >> 5, fq = (d >> 3) & 3, jj = d & 7;
        int lane = (fq << 4) | h;            // A[m=lane&15][k=(lane>>4)*8+j]
        rAf[(size_t)(i * 64 + lane) * 8 + jj] = f2bf(acc);
    } else {
        int b = bx - 64;
        int v = 0;
        for (int k = 0; k < 8; k++) v |= mask[b * N_ + k * 256 + t];
        unsigned long long bal = __ballot(v != 0);
        int w = t >> 6;
        if ((t & 63) == 0) wf[w] = (bal != 0ull) ? 1 : 0;
        __syncthreads();
        if (t == 0) any_ws[b] = wf[0] | wf[1] | wf[2] | wf[3];
    }
}

// ---------------------------------------------------------------------------
// main_k v4: grid 256, 512 threads (8 waves). K-SPLIT scores: wave w computes
// the partial score over d in [128w,+128) only (4 MFMA, 8 ds_read_b128, 8
// cvt8) -- 8x less score-phase LDS traffic + VALU than v3's redundant
// full-d-per-wave scheme. Partials reduced across waves via 8KB LDS buffer
// (256-thread reduce + exp -> shared 1KB E tile). Barriers A/B are cheap
// (vmcnt already 0 there); prefetch for tile it+1 is issued AFTER barrier B
// so its vmcnt drain lands on the end-of-tile barrier, covered by ctx.
// rA shrinks to 4 frags (16 VGPRs) -> ~100 VGPRs total, no spill.
// ---------------------------------------------------------------------------
__global__ __launch_bounds__(512, 1) void main_k(const float* __restrict__ z,
        const int* __restrict__ mask, const int* __restrict__ any_ws,
        const unsigned short* __restrict__ rAf,
        unsigned short* __restrict__ part, float* __restrict__ l_part) {
    __shared__ __align__(16) float zt[2][16 * RPAD];   // 131,584 B
    __shared__ __align__(16) float Sp[8][16][16];      // 8 KB partial scores
    __shared__ __align__(16) float E[16][16];          // 1 KB shared e[n][h]
    __shared__ float Lr[4][16];
    __shared__ int mlds[256];
    int bx = blockIdx.x, t = threadIdx.x;
    int b = bx >> 3, c = bx & 7;
    int n0 = c * 256;
    int w = t >> 6, l = t & 63;
    int frow = l & 15, fquad = l >> 4;
    int anyb = any_ws[b];

    // wave w needs only its 4 K-slice A-fragments (16 VGPRs)
    short8 rA[4];
    {
        const short8* rA8 = (const short8*)rAf;
        #pragma unroll
        for (int i = 0; i < 4; i++) rA[i] = rA8[(4 * w + i) * 64 + l];
    }
    const float* zb = z + (size_t)b * N_ * D_ + (size_t)n0 * D_;

    if (t < 256) mlds[t] = mask[b * N_ + n0 + t];

    float2 ctx[16];
    #pragma unroll
    for (int h = 0; h < 16; h++) ctx[h] = make_float2(0.f, 0.f);
    float lacc = 0.f;

    // async stage one 16-row tile: wave w loads rows 2w and 2w+1 (4 x 1KB each).
    // LDS dest is wave-uniform base + lane*16B (HW rule).
    #define STAGE(p, tile)                                                        \
        {                                                                         \
            _Pragma("unroll")                                                     \
            for (int rr = 0; rr < 2; rr++) {                                      \
                int row = 2 * w + rr;                                             \
                const float* gsrc = zb + (size_t)(tile) * 16 * D_ +               \
                                    (size_t)row * D_ + l * 4;                     \
                float* ldst = &zt[(p)][row * RPAD];                               \
                _Pragma("unroll")                                                 \
                for (int q = 0; q < 4; q++) {                                     \
                    __builtin_amdgcn_global_load_lds(                             \
                        (const __attribute__((address_space(1))) unsigned int*)   \
                            (gsrc + q * 256),                                     \
                        (__attribute__((address_space(3))) unsigned int*)         \
                            (ldst + q * 256),                                     \
                        16, 0, 0);                                                \
                }                                                                 \
            }                                                                     \
        }

    STAGE(0, 0)
    __syncthreads();   // tile 0 resident + mlds visible

    for (int it = 0; it < NT; it++) {
        int p = it & 1;

        // --- partial scores: wave w covers d in [128w,+128) (4 MFMA) ---
        {
            f32x4 a0 = {0.f, 0.f, 0.f, 0.f}, a1 = {0.f, 0.f, 0.f, 0.f};
            const float* brow = &zt[p][frow * RPAD + w * 128 + fquad * 8];
            float4 z00 = *(const float4*)(brow + 0 * 32);
            float4 z01 = *(const float4*)(brow + 0 * 32 + 4);
            float4 z10 = *(const float4*)(brow + 1 * 32);
            float4 z11 = *(const float4*)(brow + 1 * 32 + 4);
            float4 z20 = *(const float4*)(brow + 2 * 32);
            float4 z21 = *(const float4*)(brow + 2 * 32 + 4);
            float4 z30 = *(const float4*)(brow + 3 * 32);
            float4 z31 = *(const float4*)(brow + 3 * 32 + 4);
            a0 = __builtin_amdgcn_mfma_f32_16x16x32_bf16(rA[0], cvt8(z00, z01), a0, 0, 0, 0);
            a1 = __builtin_amdgcn_mfma_f32_16x16x32_bf16(rA[1], cvt8(z10, z11), a1, 0, 0, 0);
            a0 = __builtin_amdgcn_mfma_f32_16x16x32_bf16(rA[2], cvt8(z20, z21), a0, 0, 0, 0);
            a1 = __builtin_amdgcn_mfma_f32_16x16x32_bf16(rA[3], cvt8(z30, z31), a1, 0, 0, 0);
            f32x4 acc = a0 + a1;             // partial S[h=fquad*4+r][n=frow]
            *(f32x4*)&Sp[w][frow][fquad * 4] = acc;
        }
        __syncthreads();   // A: Sp visible (vmcnt already 0 here -> cheap)

        // --- reduce 8 partials + mask + exp -> shared E[n][h] ---
        if (t < 256) {
            const float* sp = &Sp[0][0][0];
            float s = sp[t] + sp[256 + t] + sp[512 + t] + sp[768 + t] +
                      sp[1024 + t] + sp[1280 + t] + sp[1536 + t] + sp[1792 + t];
            int n = t >> 4;
            int gn = n0 + it * 16 + n;
            bool valid = (mlds[it * 16 + n] != 0) || (gn == 0 && anyb == 0);
            float ev = valid ? __expf(s) : 0.f;
            lacc += ev;
            ((float*)E)[t] = ev;
        }
        __syncthreads();   // B: E visible (vmcnt still 0 -> cheap)

        if (it + 1 < NT) STAGE(p ^ 1, it + 1)   // latency covered by ctx below

        // --- ctx: wave w owns d in [128w,+128); lane covers d = 128w+2l..+1 ---
        {
            const float* zcol = &zt[p][w * 128 + 2 * l];
            #pragma unroll 4
            for (int r = 0; r < 16; r++) {
                float2 zr = *(const float2*)(zcol + r * RPAD);
                const float4* er4 = (const float4*)&E[r][0];
                float4 e0 = er4[0], e1 = er4[1], e2 = er4[2], e3 = er4[3];
                ctx[0].x  += e0.x * zr.x; ctx[0].y  += e0.x * zr.y;
                ctx[1].x  += e0.y * zr.x; ctx[1].y  += e0.y * zr.y;
                ctx[2].x  += e0.z * zr.x; ctx[2].y  += e0.z * zr.y;
                ctx[3].x  += e0.w * zr.x; ctx[3].y  += e0.w * zr.y;
                ctx[4].x  += e1.x * zr.x; ctx[4].y  += e1.x * zr.y;
                ctx[5].x  += e1.y * zr.x; ctx[5].y  += e1.y * zr.y;
                ctx[6].x  += e1.z * zr.x; ctx[6].y  += e1.z * zr.y;
                ctx[7].x  += e1.w * zr.x; ctx[7].y  += e1.w * zr.y;
                ctx[8].x  += e2.x * zr.x; ctx[8].y  += e2.x * zr.y;
                ctx[9].x  += e2.y * zr.x; ctx[9].y  += e2.y * zr.y;
                ctx[10].x += e2.z * zr.x; ctx[10].y += e2.z * zr.y;
                ctx[11].x += e2.w * zr.x; ctx[11].y += e2.w * zr.y;
                ctx[12].x += e3.x * zr.x; ctx[12].y += e3.x * zr.y;
                ctx[13].x += e3.y * zr.x; ctx[13].y += e3.y * zr.y;
                ctx[14].x += e3.z * zr.x; ctx[14].y += e3.z * zr.y;
                ctx[15].x += e3.w * zr.x; ctx[15].y += e3.w * zr.y;
            }
        }
        __syncthreads();   // C: drains prefetch vmcnt; zt[p] reads done
    }

    // --- epilogue: bf16 partials + f32 l ---
    {
        unsigned short* pp = part + (size_t)bx * 16 * 1024 + w * 128 + 2 * l;
        #pragma unroll
        for (int h = 0; h < 16; h++) {
            ushort2 o;
            o.x = f2bf(ctx[h].x); o.y = f2bf(ctx[h].y);
            *(ushort2*)(pp + h * 1024) = o;
        }
    }
    // l reduction: thread t<256 owns (n=t>>4, h=t&15); sum over n
    if (t < 256) {
        float v = lacc;
        v += __shfl_xor(v, 16, 64);
        v += __shfl_xor(v, 32, 64);
        if (l < 16) Lr[w][l] = v;   // w in 0..3 here (t<256), h = l
    }
    __syncthreads();
    if (t < 16) l_part[bx * 16 + t] = Lr[0][t] + Lr[1][t] + Lr[2][t] + Lr[3][t];
}

// ---------------------------------------------------------------------------
// gemv_wv_k: block (b,h). Phase A: vlds = (sum_c part[b][c][h][:]) / L[b][h].
// Phase B: pooled[b][64h+j] = w_v[64h+j,:].vlds + b_v (4-acc ILP GEMV).
// ---------------------------------------------------------------------------
__global__ __launch_bounds__(256) void gemv_wv_k(const unsigned short* __restrict__ part,
        const float* __restrict__ l_part, const float* __restrict__ w_v,
        const float* __restrict__ b_v, float* __restrict__ pooled) {
    __shared__ __align__(16) float vlds[1024];
    int bx = blockIdx.x, t = threadIdx.x;
    int b = bx >> 4, h = bx & 15;
    float L = 0.f;
    #pragma unroll
    for (int cc = 0; cc < 8; cc++) L += l_part[(b * 8 + cc) * 16 + h];
    float rL = 1.f / L;
    float sx = 0.f, sy = 0.f, sz = 0.f, sw = 0.f;
    #pragma unroll
    for (int cc = 0; cc < 8; cc++) {
        const ushort4* p4 = (const ushort4*)&part[(((size_t)(b * 8 + cc)) * 16 + h) * 1024];
        ushort4 u = p4[t];
        sx += bflo(u.x); sy += bflo(u.y); sz += bflo(u.z); sw += bflo(u.w);
    }
    *(float4*)&vlds[4 * t] = make_float4(sx * rL, sy * rL, sz * rL, sw * rL);
    __syncthreads();
    int w = t >> 6, l = t & 63;
    const float4* v4 = (const float4*)vlds;
    float* orow = pooled + (size_t)b * 1024;
    #pragma unroll
    for (int s0 = 0; s0 < 16; s0 += 4) {
        int jb = h * 64 + w * 16 + s0;
        float a0 = 0.f, a1 = 0.f, a2 = 0.f, a3 = 0.f;
        #pragma unroll
        for (int kk = 0; kk < 4; kk++) {
            float4 v = v4[kk * 64 + l];
            float4 w0 = *(const float4*)&w_v[(size_t)(jb + 0) * 1024 + (kk * 64 + l) * 4];
            float4 w1 = *(const float4*)&w_v[(size_t)(jb + 1) * 1024 + (kk * 64 + l) * 4];
            float4 w2 = *(const float4*)&w_v[(size_t)(jb + 2) * 1024 + (kk * 64 + l) * 4];
            float4 w3 = *(const float4*)&w_v[(size_t)(jb + 3) * 1024 + (kk * 64 + l) * 4];
            a0 += w0.x * v.x + w0.y * v.y + w0.z * v.z + w0.w * v.w;
            a1 += w1.x * v.x + w1.y * v.y + w1.z * v.z + w1.w * v.w;
            a2 += w2.x * v.x + w2.y * v.y + w2.z * v.z + w2.w * v.w;
            a3 += w3.x * v.x + w3.y * v.y + w3.z * v.z + w3.w * v.w;
        }
        #pragma unroll
        for (int m = 32; m >= 1; m >>= 1) {
            a0 += __shfl_xor(a0, m, 64); a1 += __shfl_xor(a1, m, 64);
            a2 += __shfl_xor(a2, m, 64); a3 += __shfl_xor(a3, m, 64);
        }
        if (l == 0) {
            orow[jb + 0] = a0 + b_v[jb + 0];
            orow[jb + 1] = a1 + b_v[jb + 1];
            orow[jb + 2] = a2 + b_v[jb + 2];
            orow[jb + 3] = a3 + b_v[jb + 3];
        }
    }
}

// ---------------------------------------------------------------------------
// gemv_wo_k: block (b,q). out[b][64q+j] = w_o[64q+j,:].pooled[b] + b_o
// ---------------------------------------------------------------------------
__global__ __launch_bounds__(256) void gemv_wo_k(const float* __restrict__ pooled,
        const float* __restrict__ w_o, const float* __restrict__ b_o,
        float* __restrict__ out) {
    __shared__ __align__(16) float vlds[1024];
    int bx = blockIdx.x, t = threadIdx.x;
    int b = bx >> 4, q = bx & 15;
    *(float4*)&vlds[4 * t] = *(const float4*)&pooled[(size_t)b * 1024 + 4 * t];
    __syncthreads();
    int w = t >> 6, l = t & 63;
    const float4* v4 = (const float4*)vlds;
    float* orow = out + (size_t)b * 1024;
    #pragma unroll
    for (int s0 = 0; s0 < 16; s0 += 4) {
        int jb = q * 64 + w * 16 + s0;
        float a0 = 0.f, a1 = 0.f, a2 = 0.f, a3 = 0.f;
        #pragma unroll
        for (int kk = 0; kk < 4; kk++) {
            float4 v = v4[kk * 64 + l];
            float4 w0 = *(const float4*)&w_o[(size_t)(jb + 0) * 1024 + (kk * 64 + l) * 4];
            float4 w1 = *(const float4*)&w_o[(size_t)(jb + 1) * 1024 + (kk * 64 + l) * 4];
            float4 w2 = *(const float4*)&w_o[(size_t)(jb + 2) * 1024 + (kk * 64 + l) * 4];
            float4 w3 = *(const float4*)&w_o[(size_t)(jb + 3) * 1024 + (kk * 64 + l) * 4];
            a0 += w0.x * v.x + w0.y * v.y + w0.z * v.z + w0.w * v.w;
            a1 += w1.x * v.x + w1.y * v.y + w1.z * v.z + w1.w * v.w;
            a2 += w2.x * v.x + w2.y * v.y + w2.z * v.z + w2.w * v.w;
            a3 += w3.x * v.x + w3.y * v.y + w3.z * v.z + w3.w * v.w;
        }
        #pragma unroll
        for (int m = 32; m >= 1; m >>= 1) {
            a0 += __shfl_xor(a0, m, 64); a1 += __shfl_xor(a1, m, 64);
            a2 += __shfl_xor(a2, m, 64); a3 += __shfl_xor(a3, m, 64);
        }
        if (l == 0) {
            orow[jb + 0] = a0 + b_o[jb + 0];
            orow[jb + 1] = a1 + b_o[jb + 1];
            orow[jb + 2] = a2 + b_o[jb + 2];
            orow[jb + 3] = a3 + b_o[jb + 3];
        }
    }
}

// ---------------------------------------------------------------------------
extern "C" void kernel_launch(void* const* d_in, const int* in_sizes, int n_in,
                              void* d_out, int out_size, void* d_ws, size_t ws_size,
                              hipStream_t stream) {
    const float* z     = (const float*)d_in[0];
    const int*   mask  = (const int*)d_in[1];
    const float* query = (const float*)d_in[2];
    const float* w_q   = (const float*)d_in[3];
    const float* w_k   = (const float*)d_in[4];
    const float* w_v   = (const float*)d_in[5];
    const float* b_q   = (const float*)d_in[6];
    // d_in[7] = b_k: constant per (b,h) over n -> cancels in softmax
    const float* b_v   = (const float*)d_in[8];
    const float* w_o   = (const float*)d_in[9];
    const float* b_o   = (const float*)d_in[10];
    float* out = (float*)d_out;

    char* ws = (char*)d_ws;
    unsigned short* rAf    = (unsigned short*)(ws + 0);       // 32 KB
    int*            any_ws = (int*)(ws + 32768);              // 128 B
    float*          l_part = (float*)(ws + 40960);            // 16 KB
    float*          pooled = (float*)(ws + 65536);            // 128 KB
    unsigned short* part   = (unsigned short*)(ws + 1048576); // 8 MB

    prep_k<<<96, 256, 0, stream>>>(query, w_q, b_q, w_k, mask, rAf, any_ws);
    main_k<<<256, 512, 0, stream>>>(z, mask, any_ws, rAf, part, l_part);
    gemv_wv_k<<<512, 256, 0, stream>>>(part, l_part, w_v, b_v, pooled);
    gemv_wo_k<<<512, 256, 0, stream>>>(pooled, w_o, b_o, out);
}

// Round 5
// 423.123 us; speedup vs baseline: 2.1319x; 1.0012x over previous
//
#include <hip/hip_runtime.h>
#include <hip/hip_bf16.h>
#include <stdint.h>

#define B_ 32
#define N_ 2048
#define D_ 1024
#define H_ 16

#define NT 16          // 16-row tiles per block (256 rows/block)
#define RPAD 1028      // f32 row stride in LDS (+4 pad)

typedef __attribute__((ext_vector_type(8))) short short8;
typedef __attribute__((ext_vector_type(4))) float f32x4;

// LDS-only barrier: orders ds_read/ds_write across waves WITHOUT draining
// vmcnt, so in-flight global_load_lds prefetch keeps streaming across it.
// sched_barrier(0) pins it (hipcc may hoist reg-only ops past asm; rule #18).
#define LDS_BARRIER()                                             \
    {                                                             \
        asm volatile("s_waitcnt lgkmcnt(0)\n\ts_barrier" ::: "memory"); \
        __builtin_amdgcn_sched_barrier(0);                        \
    }

__device__ __forceinline__ unsigned short f2bf(float x) {
    unsigned u = __float_as_uint(x);
    u += 0x7FFFu + ((u >> 16) & 1u);   // RNE
    return (unsigned short)(u >> 16);
}
__device__ __forceinline__ float bflo(unsigned u) { return __uint_as_float(u << 16); }

// pack 8 f32 -> short8 bf16 (RNE packed cvt)
__device__ __forceinline__ short8 cvt8(float4 a, float4 b) {
    union { __hip_bfloat162 h[4]; short8 s; } u;
    u.h[0] = __float22bfloat162_rn(make_float2(a.x, a.y));
    u.h[1] = __float22bfloat162_rn(make_float2(a.z, a.w));
    u.h[2] = __float22bfloat162_rn(make_float2(b.x, b.y));
    u.h[3] = __float22bfloat162_rn(make_float2(b.z, b.w));
    return u.s;
}

// ---------------------------------------------------------------------------
// prep_k (fused): blocks 0..63 (h=bx>>2, dg=bx&3):
//   phase 1: q_h[j] = query . w_q[64h+j,:] + b_q[64h+j]      (j in [0,64))
//   phase 2: R[h][d] = 0.125 * sum_j q_h[j] w_k[64h+j][d], d in [256dg,+256),
//            packed directly as bf16 MFMA A-fragments.
// blocks 64..95: any_ws[b] = OR over mask row (b = bx-64).
// ---------------------------------------------------------------------------
__global__ __launch_bounds__(256) void prep_k(const float* __restrict__ query,
        const float* __restrict__ w_q, const float* __restrict__ b_q,
        const float* __restrict__ w_k, const int* __restrict__ mask,
        unsigned short* __restrict__ rAf, int* __restrict__ any_ws) {
    __shared__ __align__(16) float qv[1024];
    __shared__ float qp[64][5];
    __shared__ float qh[64];
    __shared__ int wf[4];
    int bx = blockIdx.x, t = threadIdx.x;
    if (bx < 64) {
        int h = bx >> 2, dg = bx & 3;
        *(float4*)&qv[4 * t] = *(const float4*)&query[4 * t];
        __syncthreads();
        // ---- phase 1: q row (64 outputs, 4 threads per output) ----
        {
            int j = t >> 2, sub = t & 3;
            const float4* wq4 = (const float4*)(w_q + (size_t)(h * 64 + j) * 1024);
            const float4* qv4 = (const float4*)qv;
            float a = 0.f;
            #pragma unroll 8
            for (int kk = 0; kk < 64; kk++) {
                float4 wv = wq4[sub * 64 + kk];
                float4 vv = qv4[sub * 64 + kk];
                a += wv.x * vv.x + wv.y * vv.y + wv.z * vv.z + wv.w * vv.w;
            }
            qp[j][sub] = a;
        }
        __syncthreads();
        if (t < 64)
            qh[t] = qp[t][0] + qp[t][1] + qp[t][2] + qp[t][3] + b_q[h * 64 + t];
        __syncthreads();
        // ---- phase 2: R slice, pack A-fragment ----
        int d = dg * 256 + t;
        float acc = 0.f;
        #pragma unroll 8
        for (int j = 0; j < 64; j++)
            acc += qh[j] * w_k[(size_t)(h * 64 + j) * 1024 + d];
        acc *= 0.125f;                       // 1/sqrt(64) folded into R
        int i = d >> 5, fq = (d >> 3) & 3, jj = d & 7;
        int lane = (fq << 4) | h;            // A[m=lane&15][k=(lane>>4)*8+j]
        rAf[(size_t)(i * 64 + lane) * 8 + jj] = f2bf(acc);
    } else {
        int b = bx - 64;
        int v = 0;
        for (int k = 0; k < 8; k++) v |= mask[b * N_ + k * 256 + t];
        unsigned long long bal = __ballot(v != 0);
        int w = t >> 6;
        if ((t & 63) == 0) wf[w] = (bal != 0ull) ? 1 : 0;
        __syncthreads();
        if (t == 0) any_ws[b] = wf[0] | wf[1] | wf[2] | wf[3];
    }
}

// ---------------------------------------------------------------------------
// main_k v5: r4's K-split structure + T4 barrier surgery.
//  - STAGE(it+1) issued at TOP of iteration: full-iteration landing window.
//  - Barriers A/B are LDS-only (lgkmcnt+s_barrier, NO vmcnt drain) so the
//    prefetch streams across them; the single compiler __syncthreads at C
//    provides the one required vmcnt(0) drain per tile.
//  - Everything else identical to the verified r4 kernel.
// ---------------------------------------------------------------------------
__global__ __launch_bounds__(512, 1) void main_k(const float* __restrict__ z,
        const int* __restrict__ mask, const int* __restrict__ any_ws,
        const unsigned short* __restrict__ rAf,
        unsigned short* __restrict__ part, float* __restrict__ l_part) {
    __shared__ __align__(16) float zt[2][16 * RPAD];   // 131,584 B
    __shared__ __align__(16) float Sp[8][16][16];      // 8 KB partial scores
    __shared__ __align__(16) float E[16][16];          // 1 KB shared e[n][h]
    __shared__ float Lr[4][16];
    __shared__ int mlds[256];
    int bx = blockIdx.x, t = threadIdx.x;
    int b = bx >> 3, c = bx & 7;
    int n0 = c * 256;
    int w = t >> 6, l = t & 63;
    int frow = l & 15, fquad = l >> 4;
    int anyb = any_ws[b];

    // wave w needs only its 4 K-slice A-fragments (16 VGPRs)
    short8 rA[4];
    {
        const short8* rA8 = (const short8*)rAf;
        #pragma unroll
        for (int i = 0; i < 4; i++) rA[i] = rA8[(4 * w + i) * 64 + l];
    }
    const float* zb = z + (size_t)b * N_ * D_ + (size_t)n0 * D_;

    if (t < 256) mlds[t] = mask[b * N_ + n0 + t];

    float2 ctx[16];
    #pragma unroll
    for (int h = 0; h < 16; h++) ctx[h] = make_float2(0.f, 0.f);
    float lacc = 0.f;

    // async stage one 16-row tile: wave w loads rows 2w and 2w+1 (4 x 1KB each).
    // LDS dest is wave-uniform base + lane*16B (HW rule).
    #define STAGE(p, tile)                                                        \
        {                                                                         \
            _Pragma("unroll")                                                     \
            for (int rr = 0; rr < 2; rr++) {                                      \
                int row = 2 * w + rr;                                             \
                const float* gsrc = zb + (size_t)(tile) * 16 * D_ +               \
                                    (size_t)row * D_ + l * 4;                     \
                float* ldst = &zt[(p)][row * RPAD];                               \
                _Pragma("unroll")                                                 \
                for (int q = 0; q < 4; q++) {                                     \
                    __builtin_amdgcn_global_load_lds(                             \
                        (const __attribute__((address_space(1))) unsigned int*)   \
                            (gsrc + q * 256),                                     \
                        (__attribute__((address_space(3))) unsigned int*)         \
                            (ldst + q * 256),                                     \
                        16, 0, 0);                                                \
                }                                                                 \
            }                                                                     \
        }

    STAGE(0, 0)
    __syncthreads();   // tile 0 resident + mlds visible

    for (int it = 0; it < NT; it++) {
        int p = it & 1;

        // prefetch NEXT tile now: stays in flight across LDS-only barriers
        // A and B, lands during score+reduce+ctx, drained once at C.
        if (it + 1 < NT) STAGE(p ^ 1, it + 1)

        // --- partial scores: wave w covers d in [128w,+128) (4 MFMA) ---
        {
            f32x4 a0 = {0.f, 0.f, 0.f, 0.f}, a1 = {0.f, 0.f, 0.f, 0.f};
            const float* brow = &zt[p][frow * RPAD + w * 128 + fquad * 8];
            float4 z00 = *(const float4*)(brow + 0 * 32);
            float4 z01 = *(const float4*)(brow + 0 * 32 + 4);
            float4 z10 = *(const float4*)(brow + 1 * 32);
            float4 z11 = *(const float4*)(brow + 1 * 32 + 4);
            float4 z20 = *(const float4*)(brow + 2 * 32);
            float4 z21 = *(const float4*)(brow + 2 * 32 + 4);
            float4 z30 = *(const float4*)(brow + 3 * 32);
            float4 z31 = *(const float4*)(brow + 3 * 32 + 4);
            a0 = __builtin_amdgcn_mfma_f32_16x16x32_bf16(rA[0], cvt8(z00, z01), a0, 0, 0, 0);
            a1 = __builtin_amdgcn_mfma_f32_16x16x32_bf16(rA[1], cvt8(z10, z11), a1, 0, 0, 0);
            a0 = __builtin_amdgcn_mfma_f32_16x16x32_bf16(rA[2], cvt8(z20, z21), a0, 0, 0, 0);
            a1 = __builtin_amdgcn_mfma_f32_16x16x32_bf16(rA[3], cvt8(z30, z31), a1, 0, 0, 0);
            f32x4 acc = a0 + a1;             // partial S[h=fquad*4+r][n=frow]
            *(f32x4*)&Sp[w][frow][fquad * 4] = acc;
        }
        LDS_BARRIER();   // A: Sp visible; prefetch NOT drained

        // --- reduce 8 partials + mask + exp -> shared E[n][h] ---
        if (t < 256) {
            const float* sp = &Sp[0][0][0];
            float s = sp[t] + sp[256 + t] + sp[512 + t] + sp[768 + t] +
                      sp[1024 + t] + sp[1280 + t] + sp[1536 + t] + sp[1792 + t];
            int n = t >> 4;
            int gn = n0 + it * 16 + n;
            bool valid = (mlds[it * 16 + n] != 0) || (gn == 0 && anyb == 0);
            float ev = valid ? __expf(s) : 0.f;
            lacc += ev;
            ((float*)E)[t] = ev;
        }
        LDS_BARRIER();   // B: E visible; prefetch NOT drained

        // --- ctx: wave w owns d in [128w,+128); lane covers d = 128w+2l..+1 ---
        {
            const float* zcol = &zt[p][w * 128 + 2 * l];
            #pragma unroll 4
            for (int r = 0; r < 16; r++) {
                float2 zr = *(const float2*)(zcol + r * RPAD);
                const float4* er4 = (const float4*)&E[r][0];
                float4 e0 = er4[0], e1 = er4[1], e2 = er4[2], e3 = er4[3];
                ctx[0].x  += e0.x * zr.x; ctx[0].y  += e0.x * zr.y;
                ctx[1].x  += e0.y * zr.x; ctx[1].y  += e0.y * zr.y;
                ctx[2].x  += e0.z * zr.x; ctx[2].y  += e0.z * zr.y;
                ctx[3].x  += e0.w * zr.x; ctx[3].y  += e0.w * zr.y;
                ctx[4].x  += e1.x * zr.x; ctx[4].y  += e1.x * zr.y;
                ctx[5].x  += e1.y * zr.x; ctx[5].y  += e1.y * zr.y;
                ctx[6].x  += e1.z * zr.x; ctx[6].y  += e1.z * zr.y;
                ctx[7].x  += e1.w * zr.x; ctx[7].y  += e1.w * zr.y;
                ctx[8].x  += e2.x * zr.x; ctx[8].y  += e2.x * zr.y;
                ctx[9].x  += e2.y * zr.x; ctx[9].y  += e2.y * zr.y;
                ctx[10].x += e2.z * zr.x; ctx[10].y += e2.z * zr.y;
                ctx[11].x += e2.w * zr.x; ctx[11].y += e2.w * zr.y;
                ctx[12].x += e3.x * zr.x; ctx[12].y += e3.x * zr.y;
                ctx[13].x += e3.y * zr.x; ctx[13].y += e3.y * zr.y;
                ctx[14].x += e3.z * zr.x; ctx[14].y += e3.z * zr.y;
                ctx[15].x += e3.w * zr.x; ctx[15].y += e3.w * zr.y;
            }
        }
        __syncthreads();   // C: the ONE vmcnt(0) drain/tile; zt[p] reads done
    }

    // --- epilogue: bf16 partials + f32 l ---
    {
        unsigned short* pp = part + (size_t)bx * 16 * 1024 + w * 128 + 2 * l;
        #pragma unroll
        for (int h = 0; h < 16; h++) {
            ushort2 o;
            o.x = f2bf(ctx[h].x); o.y = f2bf(ctx[h].y);
            *(ushort2*)(pp + h * 1024) = o;
        }
    }
    // l reduction: thread t<256 owns (n=t>>4, h=t&15); sum over n
    if (t < 256) {
        float v = lacc;
        v += __shfl_xor(v, 16, 64);
        v += __shfl_xor(v, 32, 64);
        if (l < 16) Lr[w][l] = v;   // w in 0..3 here (t<256), h = l
    }
    __syncthreads();
    if (t < 16) l_part[bx * 16 + t] = Lr[0][t] + Lr[1][t] + Lr[2][t] + Lr[3][t];
}

// ---------------------------------------------------------------------------
// gemv_wv_k: block (b,h). Phase A: vlds = (sum_c part[b][c][h][:]) / L[b][h].
// Phase B: pooled[b][64h+j] = w_v[64h+j,:].vlds + b_v (4-acc ILP GEMV).
// ---------------------------------------------------------------------------
__global__ __launch_bounds__(256) void gemv_wv_k(const unsigned short* __restrict__ part,
        const float* __restrict__ l_part, const float* __restrict__ w_v,
        const float* __restrict__ b_v, float* __restrict__ pooled) {
    __shared__ __align__(16) float vlds[1024];
    int bx = blockIdx.x, t = threadIdx.x;
    int b = bx >> 4, h = bx & 15;
    float L = 0.f;
    #pragma unroll
    for (int cc = 0; cc < 8; cc++) L += l_part[(b * 8 + cc) * 16 + h];
    float rL = 1.f / L;
    float sx = 0.f, sy = 0.f, sz = 0.f, sw = 0.f;
    #pragma unroll
    for (int cc = 0; cc < 8; cc++) {
        const ushort4* p4 = (const ushort4*)&part[(((size_t)(b * 8 + cc)) * 16 + h) * 1024];
        ushort4 u = p4[t];
        sx += bflo(u.x); sy += bflo(u.y); sz += bflo(u.z); sw += bflo(u.w);
    }
    *(float4*)&vlds[4 * t] = make_float4(sx * rL, sy * rL, sz * rL, sw * rL);
    __syncthreads();
    int w = t >> 6, l = t & 63;
    const float4* v4 = (const float4*)vlds;
    float* orow = pooled + (size_t)b * 1024;
    #pragma unroll
    for (int s0 = 0; s0 < 16; s0 += 4) {
        int jb = h * 64 + w * 16 + s0;
        float a0 = 0.f, a1 = 0.f, a2 = 0.f, a3 = 0.f;
        #pragma unroll
        for (int kk = 0; kk < 4; kk++) {
            float4 v = v4[kk * 64 + l];
            float4 w0 = *(const float4*)&w_v[(size_t)(jb + 0) * 1024 + (kk * 64 + l) * 4];
            float4 w1 = *(const float4*)&w_v[(size_t)(jb + 1) * 1024 + (kk * 64 + l) * 4];
            float4 w2 = *(const float4*)&w_v[(size_t)(jb + 2) * 1024 + (kk * 64 + l) * 4];
            float4 w3 = *(const float4*)&w_v[(size_t)(jb + 3) * 1024 + (kk * 64 + l) * 4];
            a0 += w0.x * v.x + w0.y * v.y + w0.z * v.z + w0.w * v.w;
            a1 += w1.x * v.x + w1.y * v.y + w1.z * v.z + w1.w * v.w;
            a2 += w2.x * v.x + w2.y * v.y + w2.z * v.z + w2.w * v.w;
            a3 += w3.x * v.x + w3.y * v.y + w3.z * v.z + w3.w * v.w;
        }
        #pragma unroll
        for (int m = 32; m >= 1; m >>= 1) {
            a0 += __shfl_xor(a0, m, 64); a1 += __shfl_xor(a1, m, 64);
            a2 += __shfl_xor(a2, m, 64); a3 += __shfl_xor(a3, m, 64);
        }
        if (l == 0) {
            orow[jb + 0] = a0 + b_v[jb + 0];
            orow[jb + 1] = a1 + b_v[jb + 1];
            orow[jb + 2] = a2 + b_v[jb + 2];
            orow[jb + 3] = a3 + b_v[jb + 3];
        }
    }
}

// ---------------------------------------------------------------------------
// gemv_wo_k: block (b,q). out[b][64q+j] = w_o[64q+j,:].pooled[b] + b_o
// ---------------------------------------------------------------------------
__global__ __launch_bounds__(256) void gemv_wo_k(const float* __restrict__ pooled,
        const float* __restrict__ w_o, const float* __restrict__ b_o,
        float* __restrict__ out) {
    __shared__ __align__(16) float vlds[1024];
    int bx = blockIdx.x, t = threadIdx.x;
    int b = bx >> 4, q = bx & 15;
    *(float4*)&vlds[4 * t] = *(const float4*)&pooled[(size_t)b * 1024 + 4 * t];
    __syncthreads();
    int w = t >> 6, l = t & 63;
    const float4* v4 = (const float4*)vlds;
    float* orow = out + (size_t)b * 1024;
    #pragma unroll
    for (int s0 = 0; s0 < 16; s0 += 4) {
        int jb = q * 64 + w * 16 + s0;
        float a0 = 0.f, a1 = 0.f, a2 = 0.f, a3 = 0.f;
        #pragma unroll
        for (int kk = 0; kk < 4; kk++) {
            float4 v = v4[kk * 64 + l];
            float4 w0 = *(const float4*)&w_o[(size_t)(jb + 0) * 1024 + (kk * 64 + l) * 4];
            float4 w1 = *(const float4*)&w_o[(size_t)(jb + 1) * 1024 + (kk * 64 + l) * 4];
            float4 w2 = *(const float4*)&w_o[(size_t)(jb + 2) * 1024 + (kk * 64 + l) * 4];
            float4 w3 = *(const float4*)&w_o[(size_t)(jb + 3) * 1024 + (kk * 64 + l) * 4];
            a0 += w0.x * v.x + w0.y * v.y + w0.z * v.z + w0.w * v.w;
            a1 += w1.x * v.x + w1.y * v.y + w1.z * v.z + w1.w * v.w;
            a2 += w2.x * v.x + w2.y * v.y + w2.z * v.z + w2.w * v.w;
            a3 += w3.x * v.x + w3.y * v.y + w3.z * v.z + w3.w * v.w;
        }
        #pragma unroll
        for (int m = 32; m >= 1; m >>= 1) {
            a0 += __shfl_xor(a0, m, 64); a1 += __shfl_xor(a1, m, 64);
            a2 += __shfl_xor(a2, m, 64); a3 += __shfl_xor(a3, m, 64);
        }
        if (l == 0) {
            orow[jb + 0] = a0 + b_o[jb + 0];
            orow[jb + 1] = a1 + b_o[jb + 1];
            orow[jb + 2] = a2 + b_o[jb + 2];
            orow[jb + 3] = a3 + b_o[jb + 3];
        }
    }
}

// ---------------------------------------------------------------------------
extern "C" void kernel_launch(void* const* d_in, const int* in_sizes, int n_in,
                              void* d_out, int out_size, void* d_ws, size_t ws_size,
                              hipStream_t stream) {
    const float* z     = (const float*)d_in[0];
    const int*   mask  = (const int*)d_in[1];
    const float* query = (const float*)d_in[2];
    const float* w_q   = (const float*)d_in[3];
    const float* w_k   = (const float*)d_in[4];
    const float* w_v   = (const float*)d_in[5];
    const float* b_q   = (const float*)d_in[6];
    // d_in[7] = b_k: constant per (b,h) over n -> cancels in softmax
    const float* b_v   = (const float*)d_in[8];
    const float* w_o   = (const float*)d_in[9];
    const float* b_o   = (const float*)d_in[10];
    float* out = (float*)d_out;

    char* ws = (char*)d_ws;
    unsigned short* rAf    = (unsigned short*)(ws + 0);       // 32 KB
    int*            any_ws = (int*)(ws + 32768);              // 128 B
    float*          l_part = (float*)(ws + 40960);            // 16 KB
    float*          pooled = (float*)(ws + 65536);            // 128 KB
    unsigned short* part   = (unsigned short*)(ws + 1048576); // 8 MB

    prep_k<<<96, 256, 0, stream>>>(query, w_q, b_q, w_k, mask, rAf, any_ws);
    main_k<<<256, 512, 0, stream>>>(z, mask, any_ws, rAf, part, l_part);
    gemv_wv_k<<<512, 256, 0, stream>>>(part, l_part, w_v, b_v, pooled);
    gemv_wo_k<<<512, 256, 0, stream>>>(pooled, w_o, b_o, out);
}